// Round 16
// baseline (318.228 us; speedup 1.0000x reference)
//
#include <hip/hip_runtime.h>
#include <math.h>

#define N_NODES 65536
#define N_EDGES 524288
#define IN_CH 128
#define FHC 256
#define NCLS 3
#define NPG 32
#define NGRAPH (N_NODES / NPG)

typedef __attribute__((ext_vector_type(8))) short bfrag;   // 8 bf16 = 4 VGPR (MFMA A/B)
typedef __attribute__((ext_vector_type(4))) float facc;    // 4 f32 (MFMA C/D)

// branch-free fast gates: v_exp_f32 + v_rcp_f32; saturate correctly at +-inf
__device__ __forceinline__ float fast_sigmoid(float x) {
    return __builtin_amdgcn_rcpf(1.0f + __expf(-x));
}
__device__ __forceinline__ float fast_tanh(float x) {
    return 1.0f - 2.0f * __builtin_amdgcn_rcpf(__expf(2.0f * x) + 1.0f);
}

__device__ inline short f2bf(float f) {  // RNE float->bf16 bits
    union { float f; unsigned u; } v; v.f = f;
    unsigned r = v.u + 0x7fffu + ((v.u >> 16) & 1u);
    return (short)(r >> 16);
}
__device__ inline float bf2f(short s) {
    union { unsigned u; float f; } v; v.u = ((unsigned)(unsigned short)s) << 16;
    return v.f;
}

// async global->LDS, 16B per lane; LDS dest = wave-uniform base + lane*16 (HW)
__device__ __forceinline__ void gld16(const short* g, short* l) {
    __builtin_amdgcn_global_load_lds(
        (const __attribute__((address_space(1))) void*)g,
        (__attribute__((address_space(3))) void*)l, 16, 0, 0);
}

template <int N> __device__ __forceinline__ void vwait() {
    if constexpr (N == 0)      asm volatile("s_waitcnt vmcnt(0)" ::: "memory");
    else if constexpr (N == 1) asm volatile("s_waitcnt vmcnt(1)" ::: "memory");
    else if constexpr (N == 2) asm volatile("s_waitcnt vmcnt(2)" ::: "memory");
    else if constexpr (N == 3) asm volatile("s_waitcnt vmcnt(3)" ::: "memory");
    else if constexpr (N == 4) asm volatile("s_waitcnt vmcnt(4)" ::: "memory");
    else if constexpr (N == 5) asm volatile("s_waitcnt vmcnt(5)" ::: "memory");
    else if constexpr (N == 6) asm volatile("s_waitcnt vmcnt(6)" ::: "memory");
    else                       asm volatile("s_waitcnt vmcnt(8)" ::: "memory");
}

// ---------------- fused prep: weight convert (blocks 0..2047) + x pad (rest) ----------------
__global__ void prep_kernel(const float* __restrict__ gg_w, const float* __restrict__ wih,
                            const float* __restrict__ whh, const float* __restrict__ x,
                            short* __restrict__ gg16, short* __restrict__ wih16,
                            short* __restrict__ whh16, short* __restrict__ h) {
    int bid = blockIdx.x;
    if (bid < 2048) {
        int t = bid * 256 + threadIdx.x;  // 0 .. 8*FHC*FHC-1
        if (t < 2 * FHC * FHC) {
            gg16[t] = f2bf(gg_w[t]);
        } else if (t < 5 * FHC * FHC) {
            int u = t - 2 * FHC * FHC;
            wih16[u] = f2bf(wih[u]);
        } else {
            int u = t - 5 * FHC * FHC;
            whh16[u] = f2bf(whh[u]);
        }
    } else {
        int idx = (bid - 2048) * 256 + threadIdx.x;  // short4 granularity over N*64
        int c4 = idx & 63, n = idx >> 6;
        short4 v = {0, 0, 0, 0};
        if (c4 < 32) {
            float4 xv = reinterpret_cast<const float4*>(x)[n * 32 + c4];
            v.x = f2bf(xv.x); v.y = f2bf(xv.y); v.z = f2bf(xv.z); v.w = f2bf(xv.w);
        }
        reinterpret_cast<short4*>(h)[idx] = v;
    }
}

// ================= CSR build =================
__global__ void hist_kernel(const int* __restrict__ ei, int* __restrict__ deg) {
    int e = blockIdx.x * 256 + threadIdx.x;
    atomicAdd(&deg[ei[N_EDGES + e]], 1);
}

__global__ void scan_reduce_kernel(const int* __restrict__ deg, int* __restrict__ bsum) {
    __shared__ int s[256];
    int t = threadIdx.x;
    s[t] = deg[blockIdx.x * 256 + t];
    __syncthreads();
    for (int off = 128; off > 0; off >>= 1) {
        if (t < off) s[t] += s[t + off];
        __syncthreads();
    }
    if (t == 0) bsum[blockIdx.x] = s[0];
}

// scan_write recomputes the cross-block prefix of bsum in-LDS (replaces scan_bsum)
__global__ void scan_write_kernel(const int* __restrict__ deg, const int* __restrict__ bsum,
                                  int* __restrict__ rowptr, int* __restrict__ cur) {
    __shared__ int s[256];
    __shared__ int s2[256];
    int t = threadIdx.x, gid = blockIdx.x * 256 + t;
    int v = deg[gid];
    s[t] = v;
    int bv = bsum[t];
    s2[t] = bv;
    __syncthreads();
    for (int off = 1; off < 256; off <<= 1) {
        int u = (t >= off) ? s[t - off] : 0;
        int u2 = (t >= off) ? s2[t - off] : 0;
        __syncthreads();
        s[t] += u;
        s2[t] += u2;
        __syncthreads();
    }
    int boff = s2[blockIdx.x] - bsum[blockIdx.x];  // exclusive cross-block prefix
    int excl = boff + s[t] - v;
    rowptr[gid] = excl;
    cur[gid] = excl;
    if (gid == N_NODES - 1) rowptr[N_NODES] = excl + v;
}

__global__ void fill_kernel(const int* __restrict__ ei, const float* __restrict__ ea,
                            int* __restrict__ cur, int2* __restrict__ csr) {
    int e = blockIdx.x * 256 + threadIdx.x;
    int dst = ei[N_EDGES + e];
    int pos = atomicAdd(&cur[dst], 1);
    csr[pos] = make_int2(ei[e], __float_as_int(ea[e]));
}

// ---------------- gather: hagg[n] = sum_{e: dst=n} h[src_e] * w_e ----------------
__global__ __launch_bounds__(256) void gather_kernel(const short* __restrict__ m,
                                                     const int* __restrict__ rowptr,
                                                     const int2* __restrict__ csr,
                                                     short* __restrict__ agg16) {
    int node = blockIdx.x * 4 + (threadIdx.x >> 6);
    int lane = threadIdx.x & 63;
    int beg = rowptr[node], end = rowptr[node + 1];
    const short4* m4 = reinterpret_cast<const short4*>(m);
    float a0 = 0.f, a1 = 0.f, a2 = 0.f, a3 = 0.f;
#define GSTEP(E)                                            \
    {                                                       \
        float w = __int_as_float((E).y);                    \
        short4 v = m4[(size_t)(E).x * 64 + lane];           \
        a0 += bf2f(v.x) * w;                                \
        a1 += bf2f(v.y) * w;                                \
        a2 += bf2f(v.z) * w;                                \
        a3 += bf2f(v.w) * w;                                \
    }
    int j = beg;
    for (; j + 8 <= end; j += 8) {
        int2 e0 = csr[j + 0], e1 = csr[j + 1], e2 = csr[j + 2], e3 = csr[j + 3];
        int2 e4 = csr[j + 4], e5 = csr[j + 5], e6 = csr[j + 6], e7 = csr[j + 7];
        GSTEP(e0) GSTEP(e1) GSTEP(e2) GSTEP(e3)
        GSTEP(e4) GSTEP(e5) GSTEP(e6) GSTEP(e7)
    }
    for (; j + 2 <= end; j += 2) {
        int2 e0 = csr[j + 0], e1 = csr[j + 1];
        GSTEP(e0) GSTEP(e1)
    }
    if (j < end) {
        int2 e0 = csr[j];
        GSTEP(e0)
    }
#undef GSTEP
    short4 o;
    o.x = f2bf(a0); o.y = f2bf(a1); o.z = f2bf(a2); o.w = f2bf(a3);
    reinterpret_cast<short4*>(agg16)[(size_t)node * 64 + lane] = o;
}

// ---------------- fused-weight GEMM: both layers in one launch ----------------
// grid (6, 4): sel = by>>1 picks layer, n0 = (by&1)*128.
__global__ __launch_bounds__(256, 2) void mgemm_kernel(const short* __restrict__ A,
                                                       const short* __restrict__ Wbase,
                                                       short* __restrict__ Cbase) {
    __shared__ __align__(16) short lds[3 * 16 * 512];
    int tid = threadIdx.x;
    int lane = tid & 63, wv = tid >> 6, fr = lane & 15, fc = lane >> 4;
    int sel = blockIdx.y >> 1;
    const short* W = Wbase + (size_t)sel * FHC * FHC;
    short* C = Cbase + (size_t)sel * 3 * FHC * FHC;
    int m0 = blockIdx.x * 128, n0 = (blockIdx.y & 1) * 128;
    int srow = lane >> 2;
    int scol = (lane & 3) ^ ((lane >> 3) & 3);
    const short* gsrc[4];
    int ldsoff[4];
#pragma unroll
    for (int i = 0; i < 4; ++i) {
        int ch = wv * 4 + i;
        if (ch < 8) {
            ldsoff[i] = ch * 512;
            gsrc[i] = A + (size_t)(m0 + ch * 16 + srow) * FHC + scol * 8;
        } else {
            ldsoff[i] = 4096 + (ch - 8) * 512;
            gsrc[i] = W + (size_t)(n0 + (ch - 8) * 16 + srow) * FHC + scol * 8;
        }
    }
    int fcs = fc ^ ((fr >> 1) & 3);

    auto STAGE = [&](int ks, int bufsel) {
        short* dst = &lds[bufsel * 8192];
#pragma unroll
        for (int i = 0; i < 4; ++i) gld16(gsrc[i] + ks * 32, dst + ldsoff[i]);
    };

    facc acc[2][8] = {};
    STAGE(0, 0);
    STAGE(1, 1);
    for (int ks = 0; ks < 8; ++ks) {
        if (ks < 7) { asm volatile("s_waitcnt vmcnt(4)" ::: "memory"); }
        else        { asm volatile("s_waitcnt vmcnt(0)" ::: "memory"); }
        __builtin_amdgcn_sched_barrier(0);
        __builtin_amdgcn_s_barrier();
        __builtin_amdgcn_sched_barrier(0);
        if (ks + 2 < 8) STAGE(ks + 2, (ks + 2) % 3);
        __builtin_amdgcn_sched_barrier(0);
        const short* B = &lds[(ks % 3) * 8192];
        int ar = (wv * 32 + fr) * 32 + fcs * 8;
        bfrag a0 = *reinterpret_cast<const bfrag*>(B + ar);
        bfrag a1 = *reinterpret_cast<const bfrag*>(B + ar + 16 * 32);
        __builtin_amdgcn_s_setprio(1);
#pragma unroll
        for (int cf = 0; cf < 8; ++cf) {
            bfrag b = *reinterpret_cast<const bfrag*>(B + 4096 + (cf * 16 + fr) * 32 + fcs * 8);
            acc[0][cf] = __builtin_amdgcn_mfma_f32_16x16x32_bf16(a0, b, acc[0][cf], 0, 0, 0);
            acc[1][cf] = __builtin_amdgcn_mfma_f32_16x16x32_bf16(a1, b, acc[1][cf], 0, 0, 0);
        }
        __builtin_amdgcn_s_setprio(0);
    }
#pragma unroll
    for (int s = 0; s < 2; ++s)
#pragma unroll
        for (int cf = 0; cf < 8; ++cf)
#pragma unroll
            for (int r = 0; r < 4; ++r) {
                int node = m0 + wv * 32 + s * 16 + fc * 4 + r;
                int c = n0 + cf * 16 + fr;
                C[(size_t)node * FHC + c] = f2bf(acc[s][cf][r]);
            }
}

// ---------------- fused GG+GRU, K-split wave pairs ----------------
// 8 waves (512 thr): wave (pair = wv&3, half = wv>>2) computes gate-cols [pair*16..+16),
// K-half ks in [half*NKS/2 .. +NKS/2). Weights/wave halve (96 AGPR for NKS=8) ->
// total ~210 regs <= 256 -> guaranteed 2 waves/SIMD (R10-R14 plateau was 1 wave/SIMD at
// 316 regs vs 512/SIMD budget). Partial gate sums exchange via LDS xbuf (conflict-free
// j*64+lane layout); epilogue row-split (half 0: r=0,1; half 1: r=2,3).
template <int NKS>
__global__ __launch_bounds__(512, 2) void gru_fused_kernel(
    const short* __restrict__ hagg16, const short* __restrict__ hin, short* __restrict__ hout,
    const short* __restrict__ wfT, const short* __restrict__ whh16,
    const float* __restrict__ bih, const float* __restrict__ bhh) {
    constexpr int NKH = NKS / 2;       // ksteps per wave
    constexpr int NCH = 2 * NKS;       // chunks per tile (NKS agg + NKS h)
    constexpr int NL = NCH / 8;        // stage loads per wave (2 for NKS=8, 1 for NKS=4)
    constexpr int BUF = NCH * 512;     // shorts per staging buffer
    __shared__ __align__(16) short lds[3 * BUF + 8192];  // + 16KB xbuf
    float* xbuf = reinterpret_cast<float*>(&lds[3 * BUF]);
    int tid = threadIdx.x;
    int lane = tid & 63, wv = tid >> 6;
    int pair = wv & 3, half = wv >> 2;
    int fr = lane & 15, fc = lane >> 4;
    int c = blockIdx.y * 64 + pair * 16 + fr;  // gate column owned by this lane

    // ---- weight registers: 6 mats x NKH ksteps (this wave's K-half) ----
    bfrag wreg[6][NKH];
    {
        size_t roff = (size_t)c * FHC + fc * 8;
#pragma unroll
        for (int kk = 0; kk < NKH; ++kk) {
            int ks = half * NKH + kk;
            wreg[0][kk] = *reinterpret_cast<const bfrag*>(wfT + roff + ks * 32);
            wreg[1][kk] = *reinterpret_cast<const bfrag*>(wfT + (size_t)256 * FHC + roff + ks * 32);
            wreg[2][kk] = *reinterpret_cast<const bfrag*>(wfT + (size_t)512 * FHC + roff + ks * 32);
            wreg[3][kk] = *reinterpret_cast<const bfrag*>(whh16 + roff + ks * 32);
            wreg[4][kk] = *reinterpret_cast<const bfrag*>(whh16 + (size_t)256 * FHC + roff + ks * 32);
            wreg[5][kk] = *reinterpret_cast<const bfrag*>(whh16 + (size_t)512 * FHC + roff + ks * 32);
        }
    }
    float br = bih[c] + bhh[c];
    float bz = bih[c + 256] + bhh[c + 256];
    float big = bih[c + 512], bhg = bhh[c + 512];

    // ---- staging setup: NCH chunks, NL per wave ----
    int srow = lane >> 2;
    int scol = (lane & 3) ^ ((lane >> 3) & 3);
    const short* gb[NL];
    int ldsoff[NL];
#pragma unroll
    for (int i = 0; i < NL; ++i) {
        int ch = wv * NL + i;
        int ks = ch & (NKS - 1);
        const short* src = (ch >= NKS) ? hin : hagg16;
        gb[i] = src + (size_t)srow * FHC + ks * 32 + scol * 8;
        ldsoff[i] = ch * 512;
    }
    int fcs = fc ^ ((fr >> 1) & 3);
    int lo = (fr * 4 + fcs) * 8;
    const int NT = 32;
    int tile0 = blockIdx.x * NT;

    // hold = hin[node, c] from staged H tile; NKS=4 && c>=128 -> hin col is zero
    int cc = (NKS == 4 && c >= 128) ? 0 : c;
    int hbase = (NKS + (cc >> 5)) * 512 + (cc & 7);
    int hg = (cc >> 3) & 3;
    bool hvalid = (NKS == 8) || (c < 128);

    // xbuf addressing (floats): [pair][half][j=gate*2+d][lane]
    float* xw = xbuf + pair * 1024 + half * 512 + lane;
    const float* xr = xbuf + pair * 1024 + (1 - half) * 512 + lane;
    int row0 = fc * 4 + half * 2;  // this wave's kept rows: row0, row0+1

    auto STAGE = [&](int t, int bufsel) {
        size_t noff = (size_t)(tile0 + t) * 16 * FHC;
        short* dst = &lds[bufsel * BUF];
#pragma unroll
        for (int i = 0; i < NL; ++i) gld16(gb[i] + noff, dst + ldsoff[i]);
    };

    STAGE(0, 0);
    STAGE(1, 1);
    for (int t = 0; t < NT; ++t) {
        // drain stage(t); per wave per tile: NL stage loads + 2 stores
        if (t == 0)           vwait<NL>();
        else if (t == 1)      vwait<NL + 2>();
        else if (t == NT - 1) vwait<4>();
        else                  vwait<NL + 4>();
        __builtin_amdgcn_sched_barrier(0);
        __builtin_amdgcn_s_barrier();
        __builtin_amdgcn_sched_barrier(0);
        if (t + 2 < NT) STAGE(t + 2, (t + 2) % 3);
        __builtin_amdgcn_sched_barrier(0);
        const short* B = &lds[(t % 3) * BUF];
        facc aR = {}, aZ = {}, aG = {}, aH = {};
        __builtin_amdgcn_s_setprio(1);
#pragma unroll
        for (int kk = 0; kk < NKH; ++kk) {
            int ks = half * NKH + kk;
            bfrag ag = *reinterpret_cast<const bfrag*>(B + ks * 512 + lo);
            bfrag hh = *reinterpret_cast<const bfrag*>(B + (NKS + ks) * 512 + lo);
            aR = __builtin_amdgcn_mfma_f32_16x16x32_bf16(ag, wreg[0][kk], aR, 0, 0, 0);
            aR = __builtin_amdgcn_mfma_f32_16x16x32_bf16(hh, wreg[3][kk], aR, 0, 0, 0);
            aZ = __builtin_amdgcn_mfma_f32_16x16x32_bf16(ag, wreg[1][kk], aZ, 0, 0, 0);
            aZ = __builtin_amdgcn_mfma_f32_16x16x32_bf16(hh, wreg[4][kk], aZ, 0, 0, 0);
            aG = __builtin_amdgcn_mfma_f32_16x16x32_bf16(ag, wreg[2][kk], aG, 0, 0, 0);
            aH = __builtin_amdgcn_mfma_f32_16x16x32_bf16(hh, wreg[5][kk], aH, 0, 0, 0);
        }
        __builtin_amdgcn_s_setprio(0);
        // write donated partials (uniform branch keeps vector indices static)
        if (half == 0) {
            xw[0] = aR[2]; xw[64] = aR[3]; xw[128] = aZ[2]; xw[192] = aZ[3];
            xw[256] = aG[2]; xw[320] = aG[3]; xw[384] = aH[2]; xw[448] = aH[3];
        } else {
            xw[0] = aR[0]; xw[64] = aR[1]; xw[128] = aZ[0]; xw[192] = aZ[1];
            xw[256] = aG[0]; xw[320] = aG[1]; xw[384] = aH[0]; xw[448] = aH[1];
        }
        asm volatile("s_waitcnt lgkmcnt(0)" ::: "memory");
        __builtin_amdgcn_sched_barrier(0);
        __builtin_amdgcn_s_barrier();
        __builtin_amdgcn_sched_barrier(0);
        // reduce with partner's partials for kept rows, then epilogue (2 rows)
        float p0 = xr[0], p1 = xr[64], p2 = xr[128], p3 = xr[192];
        float p4 = xr[256], p5 = xr[320], p6 = xr[384], p7 = xr[448];
        float sR0, sR1, sZ0, sZ1, sG0, sG1, sH0, sH1;
        if (half == 0) {
            sR0 = aR[0] + p0; sR1 = aR[1] + p1; sZ0 = aZ[0] + p2; sZ1 = aZ[1] + p3;
            sG0 = aG[0] + p4; sG1 = aG[1] + p5; sH0 = aH[0] + p6; sH1 = aH[1] + p7;
        } else {
            sR0 = aR[2] + p0; sR1 = aR[3] + p1; sZ0 = aZ[2] + p2; sZ1 = aZ[3] + p3;
            sG0 = aG[2] + p4; sG1 = aG[3] + p5; sH0 = aH[2] + p6; sH1 = aH[3] + p7;
        }
        int node0 = (tile0 + t) * 16;
        {
            float hold = hvalid ? bf2f(B[hbase + (row0 * 4 + (hg ^ ((row0 >> 1) & 3))) * 8]) : 0.f;
            float rg = fast_sigmoid(sR0 + br);
            float z = fast_sigmoid(sZ0 + bz);
            float g = fast_tanh(sG0 + big + rg * (sH0 + bhg));
            hout[(size_t)(node0 + row0) * FHC + c] = f2bf(g + z * (hold - g));
        }
        {
            int row1 = row0 + 1;
            float hold = hvalid ? bf2f(B[hbase + (row1 * 4 + (hg ^ ((row1 >> 1) & 3))) * 8]) : 0.f;
            float rg = fast_sigmoid(sR1 + br);
            float z = fast_sigmoid(sZ1 + bz);
            float g = fast_tanh(sG1 + big + rg * (sH1 + bhg));
            hout[(size_t)(node0 + row1) * FHC + c] = f2bf(g + z * (hold - g));
        }
        // buf[t%3] rewritten only by STAGE(t+3), issued after barrier(t+1) -> safe.
        // xbuf rewritten at t+1 only after barrier1(t+1), by which all waves read it.
    }
}

// ---------------- fused head: conv1d(k=1) + Linear(32,256) + Linear(256,3) + softmax ------
__global__ __launch_bounds__(256) void head_kernel(
    const short* __restrict__ h, const float* __restrict__ cw, const float* __restrict__ cb,
    const float* __restrict__ l1w, const float* __restrict__ l1b,
    const float* __restrict__ l2w, const float* __restrict__ l2b, float* __restrict__ out) {
    __shared__ float ys[32];
    __shared__ float zs[256];
    __shared__ float os[3];
    int b = blockIdx.x, tid = threadIdx.x;
    {
        int node = b * 32 + (tid >> 3);
        int c0 = (tid & 7) * 32;
        const short4* hp = reinterpret_cast<const short4*>(&h[(size_t)node * FHC + c0]);
        float p = 0.f;
#pragma unroll
        for (int q = 0; q < 8; ++q) {
            short4 hv = hp[q];
            const float* wq = &cw[c0 + q * 4];
            p += fmaxf(bf2f(hv.x), 0.f) * wq[0] + fmaxf(bf2f(hv.y), 0.f) * wq[1] +
                 fmaxf(bf2f(hv.z), 0.f) * wq[2] + fmaxf(bf2f(hv.w), 0.f) * wq[3];
        }
        p += __shfl_down(p, 4, 64);
        p += __shfl_down(p, 2, 64);
        p += __shfl_down(p, 1, 64);
        if ((tid & 7) == 0) ys[tid >> 3] = fmaxf(p + cb[0], 0.f);
    }
    __syncthreads();
    float acc = l1b[tid];
#pragma unroll
    for (int k = 0; k < 32; ++k) acc += ys[k] * l1w[tid * 32 + k];
    zs[tid] = fmaxf(acc, 0.f);
    __syncthreads();
    int wave = tid >> 6, lane = tid & 63;
    if (wave < 3) {
        float p = 0.f;
#pragma unroll
        for (int j = 0; j < 4; ++j) p += zs[lane + j * 64] * l2w[wave * 256 + lane + j * 64];
#pragma unroll
        for (int off = 32; off > 0; off >>= 1) p += __shfl_down(p, off, 64);
        if (lane == 0) os[wave] = p + l2b[wave];
    }
    __syncthreads();
    if (tid == 0) {
        float mx = fmaxf(os[0], fmaxf(os[1], os[2]));
        float e0 = expf(os[0] - mx), e1 = expf(os[1] - mx), e2 = expf(os[2] - mx);
        float s = e0 + e1 + e2;
        out[b * 3 + 0] = e0 / s;
        out[b * 3 + 1] = e1 / s;
        out[b * 3 + 2] = e2 / s;
    }
}

extern "C" void kernel_launch(void* const* d_in, const int* in_sizes, int n_in,
                              void* d_out, int out_size, void* d_ws, size_t ws_size,
                              hipStream_t stream) {
    const float* x = (const float*)d_in[0];
    const int* ei = (const int*)d_in[1];
    const float* ea = (const float*)d_in[2];
    const float* gg_w = (const float*)d_in[3];
    const float* w_ih = (const float*)d_in[4];
    const float* w_hh = (const float*)d_in[5];
    const float* b_ih = (const float*)d_in[6];
    const float* b_hh = (const float*)d_in[7];
    const float* cnn_w = (const float*)d_in[8];
    const float* cnn_b = (const float*)d_in[9];
    const float* l1w = (const float*)d_in[10];
    const float* l1b = (const float*)d_in[11];
    const float* l2w = (const float*)d_in[12];
    const float* l2b = (const float*)d_in[13];
    float* out = (float*)d_out;

    const size_t nodeE = (size_t)N_NODES * FHC;
    char* p = (char*)d_ws;
    short* hA = (short*)p;      p += nodeE * 2;
    short* hB = (short*)p;      p += nodeE * 2;
    short* hagg = (short*)p;    p += nodeE * 2;
    short* gg16 = (short*)p;    p += (size_t)2 * FHC * FHC * 2;
    short* wih16 = (short*)p;   p += (size_t)3 * FHC * FHC * 2;
    short* whh16 = (short*)p;   p += (size_t)3 * FHC * FHC * 2;
    short* wfT0 = (short*)p;    p += (size_t)3 * FHC * FHC * 2;  // wfT1 contiguous after
    short* wfT1 = (short*)p;    p += (size_t)3 * FHC * FHC * 2;
    int* deg = (int*)p;         p += (size_t)N_NODES * 4;
    int* rowptr = (int*)p;      p += (size_t)(N_NODES + 4) * 4;
    int* cur = (int*)p;         p += (size_t)N_NODES * 4;
    int* bsum = (int*)p;        p += 256 * 4;
    int2* csr = (int2*)p;       p += (size_t)N_EDGES * 8;
    (void)wfT1;

    dim3 grid_wf(768 / 128, 4);  // y: [layer(2)] x [n0(2)]
    dim3 grid_gru(128, 4);

    // weights + input prep (single kernel)
    prep_kernel<<<2048 + N_NODES * 64 / 256, 256, 0, stream>>>(gg_w, w_ih, w_hh, x,
                                                               gg16, wih16, whh16, hA);

    // fused gate weights, both layers in one launch
    mgemm_kernel<<<grid_wf, 256, 0, stream>>>(wih16, gg16, wfT0);

    // CSR build (per call; graph is a fixed input)
    hipMemsetAsync(deg, 0, (size_t)N_NODES * 4, stream);
    hist_kernel<<<N_EDGES / 256, 256, 0, stream>>>(ei, deg);
    scan_reduce_kernel<<<N_NODES / 256, 256, 0, stream>>>(deg, bsum);
    scan_write_kernel<<<N_NODES / 256, 256, 0, stream>>>(deg, bsum, rowptr, cur);
    fill_kernel<<<N_EDGES / 256, 256, 0, stream>>>(ei, ea, cur, csr);

    // layer 0: gather(hA) -> hagg; GRU(hagg@Wf0, hA) -> hB   (K=128: pad zeros skipped)
    gather_kernel<<<N_NODES / 4, 256, 0, stream>>>(hA, rowptr, csr, hagg);
    gru_fused_kernel<4><<<grid_gru, 512, 0, stream>>>(hagg, hA, hB, wfT0, whh16, b_ih, b_hh);

    // layer 1: gather(hB) -> hagg; GRU(hagg@Wf1, hB) -> hA   (K=256)
    gather_kernel<<<N_NODES / 4, 256, 0, stream>>>(hB, rowptr, csr, hagg);
    gru_fused_kernel<8><<<grid_gru, 512, 0, stream>>>(hagg, hB, hA,
                                                      wfT0 + (size_t)3 * FHC * FHC, whh16,
                                                      b_ih, b_hh);

    // fused cnn + MLP head + softmax
    head_kernel<<<NGRAPH, 256, 0, stream>>>(hA, cnn_w, cnn_b, l1w, l1b, l2w, l2b, out);
}

// Round 17
// 265.788 us; speedup vs baseline: 1.1973x; 1.1973x over previous
//
#include <hip/hip_runtime.h>
#include <math.h>

#define N_NODES 65536
#define N_EDGES 524288
#define IN_CH 128
#define FHC 256
#define NCLS 3
#define NPG 32
#define NGRAPH (N_NODES / NPG)

typedef __attribute__((ext_vector_type(8))) short bfrag;   // 8 bf16 = 4 VGPR (MFMA A/B)
typedef __attribute__((ext_vector_type(4))) float facc;    // 4 f32 (MFMA C/D)

// branch-free fast gates: v_exp_f32 + v_rcp_f32; saturate correctly at +-inf
__device__ __forceinline__ float fast_sigmoid(float x) {
    return __builtin_amdgcn_rcpf(1.0f + __expf(-x));
}
__device__ __forceinline__ float fast_tanh(float x) {
    return 1.0f - 2.0f * __builtin_amdgcn_rcpf(__expf(2.0f * x) + 1.0f);
}

__device__ inline short f2bf(float f) {  // RNE float->bf16 bits
    union { float f; unsigned u; } v; v.f = f;
    unsigned r = v.u + 0x7fffu + ((v.u >> 16) & 1u);
    return (short)(r >> 16);
}
__device__ inline float bf2f(short s) {
    union { unsigned u; float f; } v; v.u = ((unsigned)(unsigned short)s) << 16;
    return v.f;
}

// async global->LDS, 16B per lane; LDS dest = wave-uniform base + lane*16 (HW)
__device__ __forceinline__ void gld16(const short* g, short* l) {
    __builtin_amdgcn_global_load_lds(
        (const __attribute__((address_space(1))) void*)g,
        (__attribute__((address_space(3))) void*)l, 16, 0, 0);
}

template <int N> __device__ __forceinline__ void vwait() {
    if constexpr (N == 0)       asm volatile("s_waitcnt vmcnt(0)" ::: "memory");
    else if constexpr (N == 2)  asm volatile("s_waitcnt vmcnt(2)" ::: "memory");
    else if constexpr (N == 4)  asm volatile("s_waitcnt vmcnt(4)" ::: "memory");
    else if constexpr (N == 6)  asm volatile("s_waitcnt vmcnt(6)" ::: "memory");
    else if constexpr (N == 8)  asm volatile("s_waitcnt vmcnt(8)" ::: "memory");
    else if constexpr (N == 10) asm volatile("s_waitcnt vmcnt(10)" ::: "memory");
    else                        asm volatile("s_waitcnt vmcnt(12)" ::: "memory");
}

// ---------------- fused prep: weight convert + x pad + deg zero (one launch) ----------------
__global__ void prep_kernel(const float* __restrict__ gg_w, const float* __restrict__ wih,
                            const float* __restrict__ whh, const float* __restrict__ x,
                            short* __restrict__ gg16, short* __restrict__ wih16,
                            short* __restrict__ whh16, short* __restrict__ h,
                            int* __restrict__ deg) {
    int bid = blockIdx.x;
    if (bid < 2048) {
        int t = bid * 256 + threadIdx.x;  // 0 .. 8*FHC*FHC-1
        if (t < 2 * FHC * FHC) {
            gg16[t] = f2bf(gg_w[t]);
        } else if (t < 5 * FHC * FHC) {
            int u = t - 2 * FHC * FHC;
            wih16[u] = f2bf(wih[u]);
        } else {
            int u = t - 5 * FHC * FHC;
            whh16[u] = f2bf(whh[u]);
        }
    } else if (bid < 2048 + N_NODES * 64 / 256) {
        int idx = (bid - 2048) * 256 + threadIdx.x;  // short4 granularity over N*64
        int c4 = idx & 63, n = idx >> 6;
        short4 v = {0, 0, 0, 0};
        if (c4 < 32) {
            float4 xv = reinterpret_cast<const float4*>(x)[n * 32 + c4];
            v.x = f2bf(xv.x); v.y = f2bf(xv.y); v.z = f2bf(xv.z); v.w = f2bf(xv.w);
        }
        reinterpret_cast<short4*>(h)[idx] = v;
    } else {
        int idx = (bid - 2048 - N_NODES * 64 / 256) * 256 + threadIdx.x;
        reinterpret_cast<int4*>(deg)[idx] = make_int4(0, 0, 0, 0);
    }
}

// ================= CSR build =================
__global__ void hist_kernel(const int* __restrict__ ei, int* __restrict__ deg) {
    int e = blockIdx.x * 256 + threadIdx.x;
    atomicAdd(&deg[ei[N_EDGES + e]], 1);
}

__global__ void scan_reduce_kernel(const int* __restrict__ deg, int* __restrict__ bsum) {
    __shared__ int s[256];
    int t = threadIdx.x;
    s[t] = deg[blockIdx.x * 256 + t];
    __syncthreads();
    for (int off = 128; off > 0; off >>= 1) {
        if (t < off) s[t] += s[t + off];
        __syncthreads();
    }
    if (t == 0) bsum[blockIdx.x] = s[0];
}

// scan_write recomputes the cross-block prefix of bsum in-LDS (replaces scan_bsum)
__global__ void scan_write_kernel(const int* __restrict__ deg, const int* __restrict__ bsum,
                                  int* __restrict__ rowptr, int* __restrict__ cur) {
    __shared__ int s[256];
    __shared__ int s2[256];
    int t = threadIdx.x, gid = blockIdx.x * 256 + t;
    int v = deg[gid];
    s[t] = v;
    int bv = bsum[t];
    s2[t] = bv;
    __syncthreads();
    for (int off = 1; off < 256; off <<= 1) {
        int u = (t >= off) ? s[t - off] : 0;
        int u2 = (t >= off) ? s2[t - off] : 0;
        __syncthreads();
        s[t] += u;
        s2[t] += u2;
        __syncthreads();
    }
    int boff = s2[blockIdx.x] - bsum[blockIdx.x];  // exclusive cross-block prefix
    int excl = boff + s[t] - v;
    rowptr[gid] = excl;
    cur[gid] = excl;
    if (gid == N_NODES - 1) rowptr[N_NODES] = excl + v;
}

__global__ void fill_kernel(const int* __restrict__ ei, const float* __restrict__ ea,
                            int* __restrict__ cur, int2* __restrict__ csr) {
    int e = blockIdx.x * 256 + threadIdx.x;
    int dst = ei[N_EDGES + e];
    int pos = atomicAdd(&cur[dst], 1);
    csr[pos] = make_int2(ei[e], __float_as_int(ea[e]));
}

// ---------------- gather: hagg[n] = sum_{e: dst=n} h[src_e] * w_e ----------------
__global__ __launch_bounds__(256) void gather_kernel(const short* __restrict__ m,
                                                     const int* __restrict__ rowptr,
                                                     const int2* __restrict__ csr,
                                                     short* __restrict__ agg16) {
    int node = blockIdx.x * 4 + (threadIdx.x >> 6);
    int lane = threadIdx.x & 63;
    int beg = rowptr[node], end = rowptr[node + 1];
    const short4* m4 = reinterpret_cast<const short4*>(m);
    float a0 = 0.f, a1 = 0.f, a2 = 0.f, a3 = 0.f;
#define GSTEP(E)                                            \
    {                                                       \
        float w = __int_as_float((E).y);                    \
        short4 v = m4[(size_t)(E).x * 64 + lane];           \
        a0 += bf2f(v.x) * w;                                \
        a1 += bf2f(v.y) * w;                                \
        a2 += bf2f(v.z) * w;                                \
        a3 += bf2f(v.w) * w;                                \
    }
    int j = beg;
    for (; j + 8 <= end; j += 8) {
        int2 e0 = csr[j + 0], e1 = csr[j + 1], e2 = csr[j + 2], e3 = csr[j + 3];
        int2 e4 = csr[j + 4], e5 = csr[j + 5], e6 = csr[j + 6], e7 = csr[j + 7];
        GSTEP(e0) GSTEP(e1) GSTEP(e2) GSTEP(e3)
        GSTEP(e4) GSTEP(e5) GSTEP(e6) GSTEP(e7)
    }
    for (; j + 2 <= end; j += 2) {
        int2 e0 = csr[j + 0], e1 = csr[j + 1];
        GSTEP(e0) GSTEP(e1)
    }
    if (j < end) {
        int2 e0 = csr[j];
        GSTEP(e0)
    }
#undef GSTEP
    short4 o;
    o.x = f2bf(a0); o.y = f2bf(a1); o.z = f2bf(a2); o.w = f2bf(a3);
    reinterpret_cast<short4*>(agg16)[(size_t)node * 64 + lane] = o;
}

// ---------------- fused-weight GEMM: both layers in one launch ----------------
// grid (6, 4): sel = by>>1 picks layer, n0 = (by&1)*128.
__global__ __launch_bounds__(256, 2) void mgemm_kernel(const short* __restrict__ A,
                                                       const short* __restrict__ Wbase,
                                                       short* __restrict__ Cbase) {
    __shared__ __align__(16) short lds[3 * 16 * 512];
    int tid = threadIdx.x;
    int lane = tid & 63, wv = tid >> 6, fr = lane & 15, fc = lane >> 4;
    int sel = blockIdx.y >> 1;
    const short* W = Wbase + (size_t)sel * FHC * FHC;
    short* C = Cbase + (size_t)sel * 3 * FHC * FHC;
    int m0 = blockIdx.x * 128, n0 = (blockIdx.y & 1) * 128;
    int srow = lane >> 2;
    int scol = (lane & 3) ^ ((lane >> 3) & 3);
    const short* gsrc[4];
    int ldsoff[4];
#pragma unroll
    for (int i = 0; i < 4; ++i) {
        int ch = wv * 4 + i;
        if (ch < 8) {
            ldsoff[i] = ch * 512;
            gsrc[i] = A + (size_t)(m0 + ch * 16 + srow) * FHC + scol * 8;
        } else {
            ldsoff[i] = 4096 + (ch - 8) * 512;
            gsrc[i] = W + (size_t)(n0 + (ch - 8) * 16 + srow) * FHC + scol * 8;
        }
    }
    int fcs = fc ^ ((fr >> 1) & 3);

    auto STAGE = [&](int ks, int bufsel) {
        short* dst = &lds[bufsel * 8192];
#pragma unroll
        for (int i = 0; i < 4; ++i) gld16(gsrc[i] + ks * 32, dst + ldsoff[i]);
    };

    facc acc[2][8] = {};
    STAGE(0, 0);
    STAGE(1, 1);
    for (int ks = 0; ks < 8; ++ks) {
        if (ks < 7) { asm volatile("s_waitcnt vmcnt(4)" ::: "memory"); }
        else        { asm volatile("s_waitcnt vmcnt(0)" ::: "memory"); }
        __builtin_amdgcn_sched_barrier(0);
        __builtin_amdgcn_s_barrier();
        __builtin_amdgcn_sched_barrier(0);
        if (ks + 2 < 8) STAGE(ks + 2, (ks + 2) % 3);
        __builtin_amdgcn_sched_barrier(0);
        const short* B = &lds[(ks % 3) * 8192];
        int ar = (wv * 32 + fr) * 32 + fcs * 8;
        bfrag a0 = *reinterpret_cast<const bfrag*>(B + ar);
        bfrag a1 = *reinterpret_cast<const bfrag*>(B + ar + 16 * 32);
        __builtin_amdgcn_s_setprio(1);
#pragma unroll
        for (int cf = 0; cf < 8; ++cf) {
            bfrag b = *reinterpret_cast<const bfrag*>(B + 4096 + (cf * 16 + fr) * 32 + fcs * 8);
            acc[0][cf] = __builtin_amdgcn_mfma_f32_16x16x32_bf16(a0, b, acc[0][cf], 0, 0, 0);
            acc[1][cf] = __builtin_amdgcn_mfma_f32_16x16x32_bf16(a1, b, acc[1][cf], 0, 0, 0);
        }
        __builtin_amdgcn_s_setprio(0);
    }
#pragma unroll
    for (int s = 0; s < 2; ++s)
#pragma unroll
        for (int cf = 0; cf < 8; ++cf)
#pragma unroll
            for (int r = 0; r < 4; ++r) {
                int node = m0 + wv * 32 + s * 16 + fc * 4 + r;
                int c = n0 + cf * 16 + fr;
                C[(size_t)node * FHC + c] = f2bf(acc[s][cf][r]);
            }
}

// ---------------- fused GG+GRU: hout = GRU(hagg @ Wf, hin) ----------------
// Proven R14/R15 structure (63.6 us): 4 waves, weight-stationary regs (plateau: 316 unified
// regs/wave -> 1 wave/SIMD; K-split alternative measured worse, R16), 3-buffer depth-2
// pipeline, one barrier/tile, LDS-hold + fast-math epilogue.
template <int NKS>
__global__ __launch_bounds__(256, 2) void gru_fused_kernel(
    const short* __restrict__ hagg16, const short* __restrict__ hin, short* __restrict__ hout,
    const short* __restrict__ wfT, const short* __restrict__ whh16,
    const float* __restrict__ bih, const float* __restrict__ bhh) {
    constexpr int NCH = 2 * NKS;      // chunks per tile (NKS agg + NKS h)
    constexpr int NL = NCH / 4;       // stage loads per wave
    constexpr int BUF = NCH * 512;    // shorts per buffer
    __shared__ __align__(16) short lds[3 * BUF];
    int tid = threadIdx.x;
    int lane = tid & 63, wv = tid >> 6, fr = lane & 15, fc = lane >> 4;
    int c = blockIdx.y * 64 + wv * 16 + fr;  // gate column owned by this lane

    // ---- weight registers: 6 mats x NKS ksteps, static-indexed (VGPR/AGPR resident) ----
    bfrag wreg[6][NKS];
    {
        size_t roff = (size_t)c * FHC + fc * 8;
#pragma unroll
        for (int ks = 0; ks < NKS; ++ks) {
            wreg[0][ks] = *reinterpret_cast<const bfrag*>(wfT + roff + ks * 32);
            wreg[1][ks] = *reinterpret_cast<const bfrag*>(wfT + (size_t)256 * FHC + roff + ks * 32);
            wreg[2][ks] = *reinterpret_cast<const bfrag*>(wfT + (size_t)512 * FHC + roff + ks * 32);
            wreg[3][ks] = *reinterpret_cast<const bfrag*>(whh16 + roff + ks * 32);
            wreg[4][ks] = *reinterpret_cast<const bfrag*>(whh16 + (size_t)256 * FHC + roff + ks * 32);
            wreg[5][ks] = *reinterpret_cast<const bfrag*>(whh16 + (size_t)512 * FHC + roff + ks * 32);
        }
    }
    float br = bih[c] + bhh[c];
    float bz = bih[c + 256] + bhh[c + 256];
    float big = bih[c + 512], bhg = bhh[c + 512];

    // ---- staging setup: NCH chunks (NKS agg + NKS h), NL per wave ----
    int srow = lane >> 2;
    int scol = (lane & 3) ^ ((lane >> 3) & 3);
    const short* gb[NL];
    int ldsoff[NL];
#pragma unroll
    for (int i = 0; i < NL; ++i) {
        int ch = wv * NL + i;
        int ks = ch & (NKS - 1);
        const short* src = (ch >= NKS) ? hin : hagg16;
        gb[i] = src + (size_t)srow * FHC + ks * 32 + scol * 8;
        ldsoff[i] = ch * 512;
    }
    int fcs = fc ^ ((fr >> 1) & 3);
    int lo = (fr * 4 + fcs) * 8;
    const int NT = 32;
    int tile0 = blockIdx.x * NT;

    // hold = hin[node, c] from staged H tile (inverse write swizzle); for NKS=4 and
    // c>=128 the column isn't staged but hin is structurally zero there -> hold = 0.
    int cc = (NKS == 4 && c >= 128) ? 0 : c;
    int hbase = (NKS + (cc >> 5)) * 512 + (cc & 7);
    int hg = (cc >> 3) & 3;
    bool hvalid = (NKS == 8) || (c < 128);

    auto STAGE = [&](int t, int bufsel) {
        size_t noff = (size_t)(tile0 + t) * 16 * FHC;
        short* dst = &lds[bufsel * BUF];
#pragma unroll
        for (int i = 0; i < NL; ++i) gld16(gb[i] + noff, dst + ldsoff[i]);
    };

    STAGE(0, 0);
    STAGE(1, 1);
    for (int t = 0; t < NT; ++t) {
        // drain stage(t): newer in-flight = {t0: NL} {t1: NL+4} {steady: NL+8} {last: 8}
        if (t == 0)           vwait<NL>();
        else if (t == 1)      vwait<NL + 4>();
        else if (t == NT - 1) vwait<8>();
        else                  vwait<NL + 8>();
        __builtin_amdgcn_sched_barrier(0);
        __builtin_amdgcn_s_barrier();
        __builtin_amdgcn_sched_barrier(0);
        if (t + 2 < NT) STAGE(t + 2, (t + 2) % 3);
        __builtin_amdgcn_sched_barrier(0);
        const short* B = &lds[(t % 3) * BUF];
        facc aR = {}, aZ = {}, aG = {}, aH = {};
        __builtin_amdgcn_s_setprio(1);
#pragma unroll
        for (int ks = 0; ks < NKS; ++ks) {
            bfrag ag = *reinterpret_cast<const bfrag*>(B + ks * 512 + lo);
            bfrag hh = *reinterpret_cast<const bfrag*>(B + (NKS + ks) * 512 + lo);
            aR = __builtin_amdgcn_mfma_f32_16x16x32_bf16(ag, wreg[0][ks], aR, 0, 0, 0);
            aR = __builtin_amdgcn_mfma_f32_16x16x32_bf16(hh, wreg[3][ks], aR, 0, 0, 0);
            aZ = __builtin_amdgcn_mfma_f32_16x16x32_bf16(ag, wreg[1][ks], aZ, 0, 0, 0);
            aZ = __builtin_amdgcn_mfma_f32_16x16x32_bf16(hh, wreg[4][ks], aZ, 0, 0, 0);
            aG = __builtin_amdgcn_mfma_f32_16x16x32_bf16(ag, wreg[2][ks], aG, 0, 0, 0);
            aH = __builtin_amdgcn_mfma_f32_16x16x32_bf16(hh, wreg[5][ks], aH, 0, 0, 0);
        }
        __builtin_amdgcn_s_setprio(0);
        int node0 = (tile0 + t) * 16;
#pragma unroll
        for (int r = 0; r < 4; ++r) {
            int row = fc * 4 + r;
            float hold = hvalid ? bf2f(B[hbase + (row * 4 + (hg ^ ((row >> 1) & 3))) * 8]) : 0.f;
            float rg = fast_sigmoid(aR[r] + br);
            float z = fast_sigmoid(aZ[r] + bz);
            float g = fast_tanh(aG[r] + big + rg * (aH[r] + bhg));
            hout[(size_t)(node0 + row) * FHC + c] = f2bf(g + z * (hold - g));
        }
        // no closing barrier: buf[t%3] is only rewritten by STAGE(t+3), issued after
        // barrier(t+1), i.e. after all waves finished reading buf[t%3].
    }
}

// ---------------- fused head: conv1d(k=1) + Linear(32,256) + Linear(256,3) + softmax ------
__global__ __launch_bounds__(256) void head_kernel(
    const short* __restrict__ h, const float* __restrict__ cw, const float* __restrict__ cb,
    const float* __restrict__ l1w, const float* __restrict__ l1b,
    const float* __restrict__ l2w, const float* __restrict__ l2b, float* __restrict__ out) {
    __shared__ float ys[32];
    __shared__ float zs[256];
    __shared__ float os[3];
    int b = blockIdx.x, tid = threadIdx.x;
    {
        int node = b * 32 + (tid >> 3);
        int c0 = (tid & 7) * 32;
        const short4* hp = reinterpret_cast<const short4*>(&h[(size_t)node * FHC + c0]);
        float p = 0.f;
#pragma unroll
        for (int q = 0; q < 8; ++q) {
            short4 hv = hp[q];
            const float* wq = &cw[c0 + q * 4];
            p += fmaxf(bf2f(hv.x), 0.f) * wq[0] + fmaxf(bf2f(hv.y), 0.f) * wq[1] +
                 fmaxf(bf2f(hv.z), 0.f) * wq[2] + fmaxf(bf2f(hv.w), 0.f) * wq[3];
        }
        p += __shfl_down(p, 4, 64);
        p += __shfl_down(p, 2, 64);
        p += __shfl_down(p, 1, 64);
        if ((tid & 7) == 0) ys[tid >> 3] = fmaxf(p + cb[0], 0.f);
    }
    __syncthreads();
    float acc = l1b[tid];
#pragma unroll
    for (int k = 0; k < 32; ++k) acc += ys[k] * l1w[tid * 32 + k];
    zs[tid] = fmaxf(acc, 0.f);
    __syncthreads();
    int wave = tid >> 6, lane = tid & 63;
    if (wave < 3) {
        float p = 0.f;
#pragma unroll
        for (int j = 0; j < 4; ++j) p += zs[lane + j * 64] * l2w[wave * 256 + lane + j * 64];
#pragma unroll
        for (int off = 32; off > 0; off >>= 1) p += __shfl_down(p, off, 64);
        if (lane == 0) os[wave] = p + l2b[wave];
    }
    __syncthreads();
    if (tid == 0) {
        float mx = fmaxf(os[0], fmaxf(os[1], os[2]));
        float e0 = expf(os[0] - mx), e1 = expf(os[1] - mx), e2 = expf(os[2] - mx);
        float s = e0 + e1 + e2;
        out[b * 3 + 0] = e0 / s;
        out[b * 3 + 1] = e1 / s;
        out[b * 3 + 2] = e2 / s;
    }
}

extern "C" void kernel_launch(void* const* d_in, const int* in_sizes, int n_in,
                              void* d_out, int out_size, void* d_ws, size_t ws_size,
                              hipStream_t stream) {
    const float* x = (const float*)d_in[0];
    const int* ei = (const int*)d_in[1];
    const float* ea = (const float*)d_in[2];
    const float* gg_w = (const float*)d_in[3];
    const float* w_ih = (const float*)d_in[4];
    const float* w_hh = (const float*)d_in[5];
    const float* b_ih = (const float*)d_in[6];
    const float* b_hh = (const float*)d_in[7];
    const float* cnn_w = (const float*)d_in[8];
    const float* cnn_b = (const float*)d_in[9];
    const float* l1w = (const float*)d_in[10];
    const float* l1b = (const float*)d_in[11];
    const float* l2w = (const float*)d_in[12];
    const float* l2b = (const float*)d_in[13];
    float* out = (float*)d_out;

    const size_t nodeE = (size_t)N_NODES * FHC;
    char* p = (char*)d_ws;
    short* hA = (short*)p;      p += nodeE * 2;
    short* hB = (short*)p;      p += nodeE * 2;
    short* hagg = (short*)p;    p += nodeE * 2;
    short* gg16 = (short*)p;    p += (size_t)2 * FHC * FHC * 2;
    short* wih16 = (short*)p;   p += (size_t)3 * FHC * FHC * 2;
    short* whh16 = (short*)p;   p += (size_t)3 * FHC * FHC * 2;
    short* wfT0 = (short*)p;    p += (size_t)3 * FHC * FHC * 2;  // wfT1 contiguous after
    short* wfT1 = (short*)p;    p += (size_t)3 * FHC * FHC * 2;
    int* deg = (int*)p;         p += (size_t)N_NODES * 4;
    int* rowptr = (int*)p;      p += (size_t)(N_NODES + 4) * 4;
    int* cur = (int*)p;         p += (size_t)N_NODES * 4;
    int* bsum = (int*)p;        p += 256 * 4;
    int2* csr = (int2*)p;       p += (size_t)N_EDGES * 8;
    (void)wfT1;

    dim3 grid_wf(768 / 128, 4);  // y: [layer(2)] x [n0(2)]
    dim3 grid_gru(128, 4);

    // weights + input prep + deg zero (single kernel, replaces memset launch)
    prep_kernel<<<2048 + N_NODES * 64 / 256 + N_NODES / 1024, 256, 0, stream>>>(
        gg_w, w_ih, w_hh, x, gg16, wih16, whh16, hA, deg);

    // fused gate weights, both layers in one launch
    mgemm_kernel<<<grid_wf, 256, 0, stream>>>(wih16, gg16, wfT0);

    // CSR build (per call; graph is a fixed input)
    hist_kernel<<<N_EDGES / 256, 256, 0, stream>>>(ei, deg);
    scan_reduce_kernel<<<N_NODES / 256, 256, 0, stream>>>(deg, bsum);
    scan_write_kernel<<<N_NODES / 256, 256, 0, stream>>>(deg, bsum, rowptr, cur);
    fill_kernel<<<N_EDGES / 256, 256, 0, stream>>>(ei, ea, cur, csr);

    // layer 0: gather(hA) -> hagg; GRU(hagg@Wf0, hA) -> hB   (K=128: pad zeros skipped)
    gather_kernel<<<N_NODES / 4, 256, 0, stream>>>(hA, rowptr, csr, hagg);
    gru_fused_kernel<4><<<grid_gru, 256, 0, stream>>>(hagg, hA, hB, wfT0, whh16, b_ih, b_hh);

    // layer 1: gather(hB) -> hagg; GRU(hagg@Wf1, hB) -> hA   (K=256)
    gather_kernel<<<N_NODES / 4, 256, 0, stream>>>(hB, rowptr, csr, hagg);
    gru_fused_kernel<8><<<grid_gru, 256, 0, stream>>>(hagg, hB, hA,
                                                      wfT0 + (size_t)3 * FHC * FHC, whh16,
                                                      b_ih, b_hh);

    // fused cnn + MLP head + softmax
    head_kernel<<<NGRAPH, 256, 0, stream>>>(hA, cnn_w, cnn_b, l1w, l1b, l2w, l2b, out);
}